// Round 1
// 80.028 us; speedup vs baseline: 1.0431x; 1.0431x over previous
//
#include <hip/hip_runtime.h>

typedef short bf16x8 __attribute__((ext_vector_type(8)));
typedef float f32x16 __attribute__((ext_vector_type(16)));

// round-to-nearest-even fp32 -> bf16 (bits)
static __device__ __forceinline__ unsigned short f2bf(float x) {
    unsigned u = __builtin_bit_cast(unsigned, x);
    unsigned r = (u + 0x7FFFu + ((u >> 16) & 1u)) >> 16;
    return (unsigned short)r;
}
static __device__ __forceinline__ float bf2f(unsigned short h) {
    unsigned u = (unsigned)h << 16;
    return __builtin_bit_cast(float, u);
}

// Workspace (shorts): A1[P*16] | A2[P*16] | B1[P*16] | B2[P*16]

// Kernel 1: per point p build MFMA K-vectors (bf16, hi/lo split) for two grams:
//   gram1: denom = 1 + s_i + s_j - 2<c_i,c_j>;  gram2: dot = <n_i,n_j>
// 32x32x16 fragment layout (verified R5-R9, absmax 0.0): point p -> tile=p>>5,
// m=p&31; k0..7 chunk -> lane m, k8..15 -> lane 32+m.
// Targets carry NEGATED normals (folds e_ss - 2 e_st + e_tt into one sum).
// Grid: 256 blocks x 64 thr (1 wave per CU across all 256 CUs) -- the gather
// chain (idx -> 9 verts) is latency-bound; spread it maximally.
__global__ void dc_pack(const float* __restrict__ verts,
                        const float* __restrict__ tnorm,
                        const float* __restrict__ tcent,
                        const int* __restrict__ idx,
                        unsigned short* __restrict__ ws,
                        float* __restrict__ out,
                        int N, int M) {
    int p = blockIdx.x * 64 + threadIdx.x;
    if (p == 0) out[0] = 0.0f;
    int P = N + M;
    if (p >= P) return;

    float cx, cy, cz, nx, ny, nz;
    if (p < N) {
        int i0 = idx[3 * p + 0], i1 = idx[3 * p + 1], i2 = idx[3 * p + 2];
        float ax = verts[3 * i0], ay = verts[3 * i0 + 1], az = verts[3 * i0 + 2];
        float bx = verts[3 * i1], by = verts[3 * i1 + 1], bz = verts[3 * i1 + 2];
        float qx = verts[3 * i2], qy = verts[3 * i2 + 1], qz = verts[3 * i2 + 2];
        float ux = ax - bx, uy = ay - by, uz = az - bz;
        float vx = qx - bx, vy = qy - by, vz = qz - bz;
        nx = 0.5f * (uy * vz - uz * vy);
        ny = 0.5f * (uz * vx - ux * vz);
        nz = 0.5f * (ux * vy - uy * vx);
        cx = (ax + bx + qx) * (1.0f / 3.0f);
        cy = (ay + by + qy) * (1.0f / 3.0f);
        cz = (az + bz + qz) * (1.0f / 3.0f);
    } else {
        int t = p - N;
        cx = tcent[3 * t]; cy = tcent[3 * t + 1]; cz = tcent[3 * t + 2];
        nx = -tnorm[3 * t]; ny = -tnorm[3 * t + 1]; nz = -tnorm[3 * t + 2];
    }

    unsigned short chx = f2bf(cx), chy = f2bf(cy), chz = f2bf(cz);
    unsigned short clx = f2bf(cx - bf2f(chx));
    unsigned short cly = f2bf(cy - bf2f(chy));
    unsigned short clz = f2bf(cz - bf2f(chz));
    unsigned short nhx = f2bf(nx), nhy = f2bf(ny), nhz = f2bf(nz);
    unsigned short nlx = f2bf(nx - bf2f(nhx));
    unsigned short nly = f2bf(ny - bf2f(nhy));
    unsigned short nlz = f2bf(nz - bf2f(nhz));
    float ex = bf2f(chx) + bf2f(clx);
    float ey = bf2f(chy) + bf2f(cly);
    float ez = bf2f(chz) + bf2f(clz);
    float s = ex * ex + ey * ey + ez * ez;
    unsigned short sh = f2bf(s), sl = f2bf(s - bf2f(sh));
    unsigned short m2hx = f2bf(-2.0f * bf2f(chx)), m2hy = f2bf(-2.0f * bf2f(chy)), m2hz = f2bf(-2.0f * bf2f(chz));
    unsigned short m2lx = f2bf(-2.0f * bf2f(clx)), m2ly = f2bf(-2.0f * bf2f(cly)), m2lz = f2bf(-2.0f * bf2f(clz));
    const unsigned short one = 0x3F80;

    __align__(16) unsigned short A1v[16] = {
        m2hx, m2hy, m2hz,  m2hx, m2hy, m2hz,  m2lx, m2ly, m2lz,
        sh, sl,  one, one,  one,  0, 0 };
    __align__(16) unsigned short B1v[16] = {
        chx, chy, chz,  clx, cly, clz,  chx, chy, chz,
        one, one,  sh, sl,  one,  0, 0 };
    __align__(16) unsigned short A2v[16] = {
        nhx, nhy, nhz,  nhx, nhy, nhz,  nlx, nly, nlz,
        0, 0, 0, 0, 0, 0, 0 };
    __align__(16) unsigned short B2v[16] = {
        nhx, nhy, nhz,  nlx, nly, nlz,  nhx, nhy, nhz,
        0, 0, 0, 0, 0, 0, 0 };

    size_t arr = (size_t)P * 16;
    unsigned short* A1 = ws;
    unsigned short* A2 = ws + arr;
    unsigned short* B1 = ws + 2 * arr;
    unsigned short* B2 = ws + 3 * arr;

    int tile = p >> 5, m = p & 31;
    size_t lo = ((size_t)tile * 64 + m) * 8;       // k0..7 -> lane m
    size_t hi = lo + 32 * 8;                       // k8..15 -> lane 32+m

    *(uint4*)(A1 + lo) = *(const uint4*)&A1v[0];
    *(uint4*)(A1 + hi) = *(const uint4*)&A1v[8];
    *(uint4*)(A2 + lo) = *(const uint4*)&A2v[0];
    *(uint4*)(A2 + hi) = *(const uint4*)&A2v[8];
    *(uint4*)(B1 + lo) = *(const uint4*)&B1v[0];
    *(uint4*)(B1 + hi) = *(const uint4*)&B1v[8];
    *(uint4*)(B2 + lo) = *(const uint4*)&B2v[0];
    *(uint4*)(B2 + hi) = *(const uint4*)&B2v[8];
}

// 8-way batched reciprocal: sum of 8 x/a terms via 1 rcp. Same VALU count as
// the old 4-way version (22 instrs per 8 elems vs 2x11) but HALF the trans-pipe
// v_rcp_f32 ops (quarter-rate pipe, ~16cy/wave64 each -- 2048cy/wave at 8/tile).
// fp32 range: denom product of 8 terms <= ~(1+|dc|^2)^8 ~ 2e14, safe.
static __device__ __forceinline__ void acc8(float4& part, const f32x16& d1, const f32x16& d2) {
#pragma unroll
    for (int g = 0; g < 2; ++g) {
        const int r = 8 * g;
        float p01 = d1[r + 0] * d1[r + 1];
        float p23 = d1[r + 2] * d1[r + 3];
        float p45 = d1[r + 4] * d1[r + 5];
        float p67 = d1[r + 6] * d1[r + 7];
        float n01 = fmaf(d2[r + 0], d1[r + 1], d2[r + 1] * d1[r + 0]);
        float n23 = fmaf(d2[r + 2], d1[r + 3], d2[r + 3] * d1[r + 2]);
        float n45 = fmaf(d2[r + 4], d1[r + 5], d2[r + 5] * d1[r + 4]);
        float n67 = fmaf(d2[r + 6], d1[r + 7], d2[r + 7] * d1[r + 6]);
        float q03 = p01 * p23;
        float q47 = p45 * p67;
        float m03 = fmaf(n01, p23, n23 * p01);
        float m47 = fmaf(n45, p67, n67 * p45);
        float T   = q03 * q47;
        float NUM = fmaf(m03, q47, m47 * q03);
        (&part.x)[g] = fmaf(NUM, __builtin_amdgcn_rcpf(T), (&part.x)[g]);
    }
}

// Kernel 2: row-paired circular symmetric sweep, hand-pipelined.
// Rows (I0=2rp, I1=I0+1) share j-window W=[I0+1, I0+256] (mod nT). Exact:
//   contrib(rp) = 2*sum_W [T(I0,j)+T(I1,j)]
//               + T(I0,I0) + T(I1,I0+257) - T(I0,I0+256) - T(I1,I0+1)
// Hot loop is unroll-2 with two NAMED buffer sets; loads for tile t+1 sit at
// the TOP of the half that processes tile t (~400 cyc of MFMA+VALU between
// issue and use), no register copies -- the scheduler cannot sink the loads
// to the loop bottom (the R9 failure mode that exposed L2 latency per iter).
// Wrap is branchless wave-uniform SALU.
// NEW: 256 blocks x 1024 thr (16 waves = one full row-pair per block; same
// 4096 waves, same 4 waves/SIMD, same 128-VGPR cap) -> 16-way LDS reduce and
// only 256 same-address device-scope atomicAdds instead of 1024 (cross-XCD
// same-line atomic RMWs serialize at the coherence point -- tail cost).
__global__ __launch_bounds__(1024, 4) void dc_pair_mfma(
    const unsigned short* __restrict__ ws, float* __restrict__ out, int P) {
    __shared__ float wsum[16];

    const int nT = P >> 5;                     // 512
    size_t arr = (size_t)P * 16;
    const unsigned short* A1 = ws;
    const unsigned short* A2 = ws + arr;
    const unsigned short* B1 = ws + 2 * arr;
    const unsigned short* B2 = ws + 3 * arr;

    int tid = threadIdx.x;
    int lane = tid & 63, wv = tid >> 6;
    int gi = blockIdx.x * 16 + wv;             // 0..4095
    int rp = gi >> 4, c = gi & 15;
    int I0 = 2 * rp, I1 = I0 + 1;

    const size_t lo = (size_t)lane * 8;

    bf16x8 a1_0 = *(const bf16x8*)(A1 + (size_t)I0 * 512 + lo);
    bf16x8 a2_0 = *(const bf16x8*)(A2 + (size_t)I0 * 512 + lo);
    bf16x8 a1_1 = *(const bf16x8*)(A1 + (size_t)I1 * 512 + lo);
    bf16x8 a2_1 = *(const bf16x8*)(A2 + (size_t)I1 * 512 + lo);

    const f32x16 zero = {0.f,0.f,0.f,0.f,0.f,0.f,0.f,0.f,0.f,0.f,0.f,0.f,0.f,0.f,0.f,0.f};
    float4 partA = make_float4(0.f, 0.f, 0.f, 0.f);
    float4 corrP = make_float4(0.f, 0.f, 0.f, 0.f);
    float4 corrM = make_float4(0.f, 0.f, 0.f, 0.f);

    auto wrap = [&](int j) -> size_t {
        return (size_t)(j >= nT ? j - nT : j) * 512;   // wave-uniform SALU
    };
    auto process = [&](const bf16x8& b1, const bf16x8& b2) {
        f32x16 d1 = __builtin_amdgcn_mfma_f32_32x32x16_bf16(a1_0, b1, zero, 0, 0, 0);
        f32x16 d2 = __builtin_amdgcn_mfma_f32_32x32x16_bf16(a2_0, b2, zero, 0, 0, 0);
        f32x16 e1 = __builtin_amdgcn_mfma_f32_32x32x16_bf16(a1_1, b1, zero, 0, 0, 0);
        f32x16 e2 = __builtin_amdgcn_mfma_f32_32x32x16_bf16(a2_1, b2, zero, 0, 0, 0);
        acc8(partA, d1, d2);
        acc8(partA, e1, e2);
    };
    auto one_tile = [&](float4& part, const bf16x8& x1, const bf16x8& x2, int jm) {
        const bf16x8 b1 = *(const bf16x8*)(B1 + (size_t)jm * 512 + lo);
        const bf16x8 b2 = *(const bf16x8*)(B2 + (size_t)jm * 512 + lo);
        f32x16 d1 = __builtin_amdgcn_mfma_f32_32x32x16_bf16(x1, b1, zero, 0, 0, 0);
        f32x16 d2 = __builtin_amdgcn_mfma_f32_32x32x16_bf16(x2, b2, zero, 0, 0, 0);
        acc8(part, d1, d2);
    };

    // chunk window: 16 j-tiles starting at I0+1+16c (mod nT; raw max 751+16)
    int js = I0 + 1 + 16 * c;

    // software pipeline: bufA holds tile t, bufB tile t+1; loads at half-tops.
    bf16x8 bA1 = *(const bf16x8*)(B1 + wrap(js) + lo);
    bf16x8 bA2 = *(const bf16x8*)(B2 + wrap(js) + lo);
#pragma unroll 1
    for (int it = 0; it < 16; it += 2) {
        size_t o1 = wrap(js + it + 1);
        bf16x8 bB1 = *(const bf16x8*)(B1 + o1 + lo);   // load t+1 (top)
        bf16x8 bB2 = *(const bf16x8*)(B2 + o1 + lo);
        process(bA1, bA2);                             // tile t
        size_t o2 = wrap(js + it + 2);                 // t+2 (last round: valid
        bA1 = *(const bf16x8*)(B1 + o2 + lo);          //  wrapped tile, unused)
        bA2 = *(const bf16x8*)(B2 + o2 + lo);
        process(bB1, bB2);                             // tile t+1
    }

    if (c == 0) {
        one_tile(corrP, a1_0, a2_0, I0);                    // +T(I0,I0)
        one_tile(corrM, a1_1, a2_1, I0 + 1);                // -T(I1,I0+1)
    } else if (c == 15) {
        int v = I0 + 256; if (v >= nT) v -= nT;
        int y = I0 + 257; if (y >= nT) y -= nT;
        one_tile(corrM, a1_0, a2_0, v);                     // -T(I0,I0+256)
        one_tile(corrP, a1_1, a2_1, y);                     // +T(I1,I0+257)
    }

    float s = 2.0f * (partA.x + partA.y + partA.z + partA.w)
            + (corrP.x + corrP.y + corrP.z + corrP.w)
            - (corrM.x + corrM.y + corrM.z + corrM.w);
#pragma unroll
    for (int off = 32; off > 0; off >>= 1) s += __shfl_down(s, off, 64);
    if (lane == 0) wsum[wv] = s;
    __syncthreads();
    if (tid == 0) {
        float t = 0.f;
#pragma unroll
        for (int i = 0; i < 16; ++i) t += wsum[i];
        atomicAdd(out, t);
    }
}

extern "C" void kernel_launch(void* const* d_in, const int* in_sizes, int n_in,
                              void* d_out, int out_size, void* d_ws, size_t ws_size,
                              hipStream_t stream) {
    const float* verts = (const float*)d_in[0];   // (V,3) f32
    const float* tnorm = (const float*)d_in[1];   // (M,3) f32
    const float* tcent = (const float*)d_in[2];   // (M,3) f32
    const int*   sidx  = (const int*)d_in[3];     // (N,3) i32

    int M = in_sizes[1] / 3;
    int N = in_sizes[3] / 3;
    int P = N + M;                                // 16384

    unsigned short* ws = (unsigned short*)d_ws;   // A1|A2|B1|B2 = 4 MB
    float* out = (float*)d_out;

    int pblocks = (P + 63) / 64;                  // 256 blocks x 64 thr
    dc_pack<<<pblocks, 64, 0, stream>>>(verts, tnorm, tcent, sidx, ws, out, N, M);

    // 256 blocks x 16 waves = 4096 waves (1 block/CU, 4 waves/SIMD, one batch)
    dc_pair_mfma<<<256, 1024, 0, stream>>>(ws, out, P);
}